// Round 1
// baseline (4520.952 us; speedup 1.0000x reference)
//
#include <hip/hip_runtime.h>
#include <hip/hip_bf16.h>
#include <math.h>
#include <stdint.h>

using bf16 = __hip_bfloat16;
typedef __attribute__((ext_vector_type(8))) short short8;   // 8 bf16 = 4 VGPRs (MFMA A/B frag)
typedef __attribute__((ext_vector_type(4))) float floatx4;  // MFMA C/D frag

#define BM 128
#define BN 128
#define BK 32

typedef const __attribute__((address_space(1))) void* gptr_t;
typedef __attribute__((address_space(3))) void* lptr_t;

// async global->LDS, 16B per lane. LDS dest = wave-uniform base + lane*16.
__device__ __forceinline__ void load_lds16(const bf16* g, bf16* l) {
    __builtin_amdgcn_global_load_lds((gptr_t)(uintptr_t)(const void*)g,
                                     (lptr_t)(uintptr_t)(void*)l, 16, 0, 0);
}

// Core 128x128 tile GEMM: C[m][n] = sum_k A[m][k] * W[n][k]
// A: (M,K) bf16 row-major; W: (N,K) bf16 row-major (i.e. B^T layout).
// Both tiles stage identically. XOR-swizzled chunk placement: global chunk s
// (16B, k-range s*8..s*8+7) of row r lands at LDS chunk position s^(r&3),
// making the quad-strided ds_read_b128 fragment reads bank-conflict-free.
__device__ __forceinline__ void gemm_core(const bf16* __restrict__ A,
                                          const bf16* __restrict__ W,
                                          int K, floatx4 acc[4][4],
                                          bf16* lA, bf16* lB) {
    const int tid  = threadIdx.x;
    const int lane = tid & 63;
    const int w    = tid >> 6;
    const int wr   = w >> 1, wc = w & 1;
    const int quad = lane >> 4, l16 = lane & 15;

    const int brow = blockIdx.y * BM;   // A rows
    const int bcol = blockIdx.x * BN;   // W rows = out cols

    // staging: 512 chunks/tile (128 rows x 4 chunks), 2 per thread
    const int c0 = tid, c1 = tid + 256;
    const int r0 = c0 >> 2, s0c = (c0 & 3) ^ (r0 & 3);
    const int r1 = c1 >> 2, s1c = (c1 & 3) ^ (r1 & 3);

    const bf16* gA0 = A + (size_t)(brow + r0) * K + s0c * 8;
    const bf16* gA1 = A + (size_t)(brow + r1) * K + s1c * 8;
    const bf16* gW0 = W + (size_t)(bcol + r0) * K + s0c * 8;
    const bf16* gW1 = W + (size_t)(bcol + r1) * K + s1c * 8;
    bf16* lA0 = lA + c0 * 8;  bf16* lA1 = lA + c1 * 8;
    bf16* lB0 = lB + c0 * 8;  bf16* lB1 = lB + c1 * 8;

    floatx4 zero = {0.f, 0.f, 0.f, 0.f};
#pragma unroll
    for (int mt = 0; mt < 4; ++mt)
#pragma unroll
        for (int nt = 0; nt < 4; ++nt) acc[mt][nt] = zero;

    const int arow = wr * 64 + l16;           // + mt*16
    const int brw  = wc * 64 + l16;           // + nt*16
    const int sw   = (quad ^ (l16 & 3)) * 8;  // swizzled k-chunk for this quad

    const int nIter = K / BK;
    for (int kt = 0; kt < nIter; ++kt) {
        load_lds16(gA0, lA0);
        load_lds16(gA1, lA1);
        load_lds16(gW0, lB0);
        load_lds16(gW1, lB1);
        __syncthreads();

        short8 af[4], bfr[4];
#pragma unroll
        for (int mt = 0; mt < 4; ++mt)
            af[mt] = *(const short8*)(lA + (arow + mt * 16) * BK + sw);
#pragma unroll
        for (int nt = 0; nt < 4; ++nt)
            bfr[nt] = *(const short8*)(lB + (brw + nt * 16) * BK + sw);
#pragma unroll
        for (int mt = 0; mt < 4; ++mt)
#pragma unroll
            for (int nt = 0; nt < 4; ++nt)
                acc[mt][nt] = __builtin_amdgcn_mfma_f32_16x16x32_bf16(
                    af[mt], bfr[nt], acc[mt][nt], 0, 0, 0);
        __syncthreads();

        gA0 += BK; gA1 += BK; gW0 += BK; gW1 += BK;
    }
}

// GEMM + bias + tanh -> bf16 out (layers 1 and 2)
__global__ void __launch_bounds__(256)
gemm_tanh(const bf16* __restrict__ A, const bf16* __restrict__ W,
          const float* __restrict__ bias, bf16* __restrict__ out,
          int K, int N) {
    __shared__ alignas(16) bf16 lA[BM * BK];
    __shared__ alignas(16) bf16 lB[BN * BK];
    floatx4 acc[4][4];
    gemm_core(A, W, K, acc, lA, lB);

    const int tid = threadIdx.x;
    const int lane = tid & 63, w = tid >> 6;
    const int wr = w >> 1, wc = w & 1;
    const int quad = lane >> 4, l16 = lane & 15;
    const int m0 = blockIdx.y * BM + wr * 64 + quad * 4;
    const int n0 = blockIdx.x * BN + wc * 64 + l16;

#pragma unroll
    for (int mt = 0; mt < 4; ++mt)
#pragma unroll
        for (int nt = 0; nt < 4; ++nt) {
            const int n = n0 + nt * 16;
            const float b = bias[n];
#pragma unroll
            for (int i = 0; i < 4; ++i) {
                const int m = m0 + mt * 16 + i;
                out[(size_t)m * N + n] = __float2bfloat16(tanhf(acc[mt][nt][i] + b));
            }
        }
}

// Layer-3 GEMM (N=512) with fused RK4 logic.
// kv = acc + b3[n]
// mode 0 (k1):   kacc = kv;        x0 = bf16(h + alpha*kv + temb)
// mode 1 (k2/3): kacc += 2*kv;     x0 = bf16(h + alpha*kv + temb)
// mode 2 (k4):   hn = h + dt6*(kacc + kv); h_out = hn;
//                if (x0_out) x0 = bf16(hn + temb)
__global__ void __launch_bounds__(256)
gemm_k(const bf16* __restrict__ A, const bf16* __restrict__ W,
       const float* __restrict__ bias, int K,
       float* __restrict__ kacc, const float* __restrict__ h_src,
       float* __restrict__ h_out, bf16* __restrict__ x0_out,
       const float* __restrict__ temb, float alpha, float dt6, int mode) {
    __shared__ alignas(16) bf16 lA[BM * BK];
    __shared__ alignas(16) bf16 lB[BN * BK];
    floatx4 acc[4][4];
    gemm_core(A, W, K, acc, lA, lB);

    const int tid = threadIdx.x;
    const int lane = tid & 63, w = tid >> 6;
    const int wr = w >> 1, wc = w & 1;
    const int quad = lane >> 4, l16 = lane & 15;
    const int m0 = blockIdx.y * BM + wr * 64 + quad * 4;
    const int n0 = blockIdx.x * BN + wc * 64 + l16;

#pragma unroll
    for (int mt = 0; mt < 4; ++mt)
#pragma unroll
        for (int nt = 0; nt < 4; ++nt) {
            const int n = n0 + nt * 16;
            const float b = bias[n];
            const float te = temb[n];
#pragma unroll
            for (int i = 0; i < 4; ++i) {
                const int m = m0 + mt * 16 + i;
                const size_t idx = (size_t)m * 512 + n;
                const float kv = acc[mt][nt][i] + b;
                if (mode == 0) {
                    kacc[idx] = kv;
                    x0_out[idx] = __float2bfloat16(h_src[idx] + alpha * kv + te);
                } else if (mode == 1) {
                    kacc[idx] += 2.f * kv;
                    x0_out[idx] = __float2bfloat16(h_src[idx] + alpha * kv + te);
                } else {
                    const float hn = h_src[idx] + dt6 * (kacc[idx] + kv);
                    h_out[idx] = hn;
                    if (x0_out) x0_out[idx] = __float2bfloat16(hn + te);
                }
            }
        }
}

__global__ void f2b_kern(const float* __restrict__ src, bf16* __restrict__ dst, int n) {
    const int i = blockIdx.x * blockDim.x + threadIdx.x;
    if (i < n) dst[i] = __float2bfloat16(src[i]);
}

// temb[j][n] = (j*dt/2)*Wt[n] + bt[n], j = 0..20
__global__ void temb_kern(const float* __restrict__ Wt, const float* __restrict__ bt,
                          float* __restrict__ temb, float half_dt, int total) {
    const int i = blockIdx.x * blockDim.x + threadIdx.x;
    if (i < total) {
        const int j = i >> 9, n = i & 511;
        temb[i] = (j * half_dt) * Wt[n] + bt[n];
    }
}

__global__ void prep_kern(const float* __restrict__ h, const float* __restrict__ temb0,
                          bf16* __restrict__ x0, int total) {
    const int i = blockIdx.x * blockDim.x + threadIdx.x;
    if (i < total) x0[i] = __float2bfloat16(h[i] + temb0[i & 511]);
}

extern "C" void kernel_launch(void* const* d_in, const int* in_sizes, int n_in,
                              void* d_out, int out_size, void* d_ws, size_t ws_size,
                              hipStream_t stream) {
    const float* h_in = (const float*)d_in[0];
    const float* W1 = (const float*)d_in[1];
    const float* b1 = (const float*)d_in[2];
    const float* W2 = (const float*)d_in[3];
    const float* b2 = (const float*)d_in[4];
    const float* W3 = (const float*)d_in[5];
    const float* b3 = (const float*)d_in[6];
    const float* Wt = (const float*)d_in[7];
    const float* bt = (const float*)d_in[8];
    // n_steps (d_in[9]) is a fixed Python scalar = 10; host needs it for launch count.
    const int B = 8192, H = 512, H2 = 1024, NS = 10;
    const float dt = 1.f / NS;

    char* ws = (char*)d_ws;
    auto alloc = [&](size_t bytes) {
        char* p = ws;
        ws += (bytes + 255) & ~(size_t)255;
        return p;
    };
    bf16* W1b = (bf16*)alloc((size_t)H2 * H * 2);
    bf16* W2b = (bf16*)alloc((size_t)H2 * H2 * 2);
    bf16* W3b = (bf16*)alloc((size_t)H * H2 * 2);
    bf16* x0b = (bf16*)alloc((size_t)B * H * 2);
    bf16* x1b = (bf16*)alloc((size_t)B * H2 * 2);
    bf16* x2b = (bf16*)alloc((size_t)B * H2 * 2);
    float* kacc = (float*)alloc((size_t)B * H * 4);
    float* temb = (float*)alloc((size_t)21 * H * 4);
    float* hbuf = (float*)d_out;  // h ping-pongs through d_out (fp32)

    // weights -> bf16
    {
        int n = H2 * H;
        f2b_kern<<<(n + 255) / 256, 256, 0, stream>>>(W1, W1b, n);
        n = H2 * H2;
        f2b_kern<<<(n + 255) / 256, 256, 0, stream>>>(W2, W2b, n);
        n = H * H2;
        f2b_kern<<<(n + 255) / 256, 256, 0, stream>>>(W3, W3b, n);
    }
    {
        const int total = 21 * H;
        temb_kern<<<(total + 255) / 256, 256, 0, stream>>>(Wt, bt, temb, dt * 0.5f, total);
    }
    {
        const int total = B * H;
        prep_kern<<<(total + 255) / 256, 256, 0, stream>>>(h_in, temb, x0b, total);
    }

    const dim3 blk(256);
    const dim3 g1(H2 / BN, B / BM);  // N=1024
    const dim3 g2(H2 / BN, B / BM);  // N=1024
    const dim3 g3(H / BN, B / BM);   // N=512

    for (int s = 0; s < NS; ++s) {
        const float* hs = (s == 0) ? h_in : hbuf;
        const float* tmid = temb + (size_t)(2 * s + 1) * H;
        const float* tend = temb + (size_t)(2 * s + 2) * H;
        for (int e = 0; e < 4; ++e) {
            gemm_tanh<<<g1, blk, 0, stream>>>(x0b, W1b, b1, x1b, H, H2);
            gemm_tanh<<<g2, blk, 0, stream>>>(x1b, W2b, b2, x2b, H2, H2);
            if (e == 0)
                gemm_k<<<g3, blk, 0, stream>>>(x2b, W3b, b3, H2, kacc, hs, nullptr,
                                               x0b, tmid, dt * 0.5f, 0.f, 0);
            else if (e == 1)
                gemm_k<<<g3, blk, 0, stream>>>(x2b, W3b, b3, H2, kacc, hs, nullptr,
                                               x0b, tmid, dt * 0.5f, 0.f, 1);
            else if (e == 2)
                gemm_k<<<g3, blk, 0, stream>>>(x2b, W3b, b3, H2, kacc, hs, nullptr,
                                               x0b, tend, dt, 0.f, 1);
            else
                gemm_k<<<g3, blk, 0, stream>>>(x2b, W3b, b3, H2, kacc, hs, hbuf,
                                               (s == NS - 1) ? nullptr : x0b,
                                               tend, 0.f, dt / 6.f, 2);
        }
    }
}

// Round 2
// 3040.153 us; speedup vs baseline: 1.4871x; 1.4871x over previous
//
#include <hip/hip_runtime.h>
#include <hip/hip_bf16.h>
#include <math.h>
#include <stdint.h>

using bf16 = __hip_bfloat16;
typedef __attribute__((ext_vector_type(8))) short short8;   // 8 bf16 = 4 VGPRs (MFMA A/B frag)
typedef __attribute__((ext_vector_type(4))) float floatx4;  // MFMA C/D frag

typedef const __attribute__((address_space(1))) void* gptr_t;
typedef __attribute__((address_space(3))) void* lptr_t;

// async global->LDS, 16B per lane. LDS dest = wave-uniform base + lane*16.
__device__ __forceinline__ void load_lds16(const bf16* g, bf16* l) {
    __builtin_amdgcn_global_load_lds((gptr_t)(uintptr_t)(const void*)g,
                                     (lptr_t)(uintptr_t)(void*)l, 16, 0, 0);
}

// tanh(x) = 1 - 2/(exp(2x)+1); saturates correctly at +-inf; err << bf16 ulp.
__device__ __forceinline__ float fast_tanh(float x) {
    float e = __expf(2.f * x);
    return 1.f - 2.f / (e + 1.f);
}

// Tiled GEMM core: C[m][n] = sum_k A[m][k] * W[n][k]
// A: (M,K) bf16 row-major; W: (N,K) bf16 row-major (B^T layout) -> same staging.
// BK = 64 (row stride 128 B). XOR-8 chunk swizzle: LDS slot p of row r holds
// global 16B chunk s = p ^ (r&7); fragment reads then hit each bank exactly
// 2-way (free). WR x WC waves; wave tile (BM/WR) x (BN/WC).
template<int BM, int BN, int WR, int WC>
__device__ __forceinline__ void gemm_core(const bf16* __restrict__ A,
                                          const bf16* __restrict__ W,
                                          int K,
                                          floatx4 (&acc)[BM / WR / 16][BN / WC / 16],
                                          bf16* lA, bf16* lB) {
    constexpr int MT = BM / WR / 16, NT = BN / WC / 16;
    constexpr int THREADS = WR * WC * 64;
    constexpr int AL = BM * 8 / THREADS;   // A chunks per thread
    constexpr int BL = BN * 8 / THREADS;   // W chunks per thread

    const int tid  = threadIdx.x;
    const int lane = tid & 63;
    const int w    = tid >> 6;
    const int wr   = w / WC, wc = w % WC;
    const int quad = lane >> 4, l16 = lane & 15;

    const int brow = blockIdx.y * BM;
    const int bcol = blockIdx.x * BN;

    const bf16* gA[AL]; const bf16* gW[BL];
    bf16* lAd[AL]; bf16* lBd[BL];
#pragma unroll
    for (int j = 0; j < AL; ++j) {
        const int q = tid + j * THREADS;
        const int r = q >> 3, s = (q & 7) ^ (r & 7);
        gA[j]  = A + (size_t)(brow + r) * K + s * 8;
        lAd[j] = lA + q * 8;
    }
#pragma unroll
    for (int j = 0; j < BL; ++j) {
        const int q = tid + j * THREADS;
        const int r = q >> 3, s = (q & 7) ^ (r & 7);
        gW[j]  = W + (size_t)(bcol + r) * K + s * 8;
        lBd[j] = lB + q * 8;
    }

    const floatx4 zero = {0.f, 0.f, 0.f, 0.f};
#pragma unroll
    for (int mt = 0; mt < MT; ++mt)
#pragma unroll
        for (int nt = 0; nt < NT; ++nt) acc[mt][nt] = zero;

    const int arow = wr * (BM / WR) + l16;   // + mt*16 ; all terms but l16 are %8==0
    const int brw  = wc * (BN / WC) + l16;   // + nt*16
    const int x7   = l16 & 7;

    const int nIter = K / 64;
    for (int kt = 0; kt < nIter; ++kt) {
#pragma unroll
        for (int j = 0; j < AL; ++j) load_lds16(gA[j], lAd[j]);
#pragma unroll
        for (int j = 0; j < BL; ++j) load_lds16(gW[j], lBd[j]);
        __syncthreads();

#pragma unroll
        for (int kk = 0; kk < 2; ++kk) {
            const int sw = ((kk * 4 + quad) ^ x7) * 8;
            short8 af[MT], bfr[NT];
#pragma unroll
            for (int mt = 0; mt < MT; ++mt)
                af[mt] = *(const short8*)(lA + (arow + mt * 16) * 64 + sw);
#pragma unroll
            for (int nt = 0; nt < NT; ++nt)
                bfr[nt] = *(const short8*)(lB + (brw + nt * 16) * 64 + sw);
#pragma unroll
            for (int mt = 0; mt < MT; ++mt)
#pragma unroll
                for (int nt = 0; nt < NT; ++nt)
                    acc[mt][nt] = __builtin_amdgcn_mfma_f32_16x16x32_bf16(
                        af[mt], bfr[nt], acc[mt][nt], 0, 0, 0);
        }
        __syncthreads();

#pragma unroll
        for (int j = 0; j < AL; ++j) gA[j] += 64;
#pragma unroll
        for (int j = 0; j < BL; ++j) gW[j] += 64;
    }
}

// GEMM + bias + tanh -> bf16 (layers 1, 2). 128x128 tile, 8 waves (2x4).
template<int BM, int BN, int WR, int WC>
__global__ void __launch_bounds__(WR * WC * 64, 4)
gemm_tanh(const bf16* __restrict__ A, const bf16* __restrict__ W,
          const float* __restrict__ bias, bf16* __restrict__ out,
          int K, int N) {
    constexpr int MT = BM / WR / 16, NT = BN / WC / 16;
    __shared__ alignas(16) bf16 lA[BM * 64];
    __shared__ alignas(16) bf16 lB[BN * 64];
    floatx4 acc[MT][NT];
    gemm_core<BM, BN, WR, WC>(A, W, K, acc, lA, lB);

    const int tid = threadIdx.x;
    const int lane = tid & 63, w = tid >> 6;
    const int wr = w / WC, wc = w % WC;
    const int quad = lane >> 4, l16 = lane & 15;
    const int m0 = blockIdx.y * BM + wr * (BM / WR) + quad * 4;
    const int n0 = blockIdx.x * BN + wc * (BN / WC) + l16;

#pragma unroll
    for (int mt = 0; mt < MT; ++mt)
#pragma unroll
        for (int nt = 0; nt < NT; ++nt) {
            const int n = n0 + nt * 16;
            const float b = bias[n];
#pragma unroll
            for (int i = 0; i < 4; ++i) {
                const int m = m0 + mt * 16 + i;
                out[(size_t)m * N + n] = __float2bfloat16(fast_tanh(acc[mt][nt][i] + b));
            }
        }
}

// Layer-3 GEMM (N=512, K=1024) with fused RK4 logic. 64x64 tile, 4 waves (2x2).
// kv = acc + b3[n]
// mode 0 (k1):   kacc = kv;        x0 = bf16(h + alpha*kv + temb)
// mode 1 (k2/3): kacc += 2*kv;     x0 = bf16(h + alpha*kv + temb)
// mode 2 (k4):   hn = h + dt6*(kacc + kv); h_out = hn; if (x0_out) x0 = bf16(hn + temb)
__global__ void __launch_bounds__(256, 4)
gemm_k(const bf16* __restrict__ A, const bf16* __restrict__ W,
       const float* __restrict__ bias, int K,
       float* __restrict__ kacc, const float* __restrict__ h_src,
       float* __restrict__ h_out, bf16* __restrict__ x0_out,
       const float* __restrict__ temb, float alpha, float dt6, int mode) {
    constexpr int BM = 64, BN = 64, WR = 2, WC = 2;
    constexpr int MT = 2, NT = 2;
    __shared__ alignas(16) bf16 lA[BM * 64];
    __shared__ alignas(16) bf16 lB[BN * 64];
    floatx4 acc[MT][NT];
    gemm_core<BM, BN, WR, WC>(A, W, K, acc, lA, lB);

    const int tid = threadIdx.x;
    const int lane = tid & 63, w = tid >> 6;
    const int wr = w / WC, wc = w % WC;
    const int quad = lane >> 4, l16 = lane & 15;
    const int m0 = blockIdx.y * BM + wr * (BM / WR) + quad * 4;
    const int n0 = blockIdx.x * BN + wc * (BN / WC) + l16;

#pragma unroll
    for (int mt = 0; mt < MT; ++mt)
#pragma unroll
        for (int nt = 0; nt < NT; ++nt) {
            const int n = n0 + nt * 16;
            const float b = bias[n];
            const float te = temb[n];
#pragma unroll
            for (int i = 0; i < 4; ++i) {
                const int m = m0 + mt * 16 + i;
                const size_t idx = (size_t)m * 512 + n;
                const float kv = acc[mt][nt][i] + b;
                if (mode == 0) {
                    kacc[idx] = kv;
                    x0_out[idx] = __float2bfloat16(h_src[idx] + alpha * kv + te);
                } else if (mode == 1) {
                    kacc[idx] += 2.f * kv;
                    x0_out[idx] = __float2bfloat16(h_src[idx] + alpha * kv + te);
                } else {
                    const float hn = h_src[idx] + dt6 * (kacc[idx] + kv);
                    h_out[idx] = hn;
                    if (x0_out) x0_out[idx] = __float2bfloat16(hn + te);
                }
            }
        }
}

__global__ void f2b_kern(const float* __restrict__ src, bf16* __restrict__ dst, int n) {
    const int i = blockIdx.x * blockDim.x + threadIdx.x;
    if (i < n) dst[i] = __float2bfloat16(src[i]);
}

// temb[j][n] = (j*dt/2)*Wt[n] + bt[n], j = 0..20
__global__ void temb_kern(const float* __restrict__ Wt, const float* __restrict__ bt,
                          float* __restrict__ temb, float half_dt, int total) {
    const int i = blockIdx.x * blockDim.x + threadIdx.x;
    if (i < total) {
        const int j = i >> 9, n = i & 511;
        temb[i] = (j * half_dt) * Wt[n] + bt[n];
    }
}

__global__ void prep_kern(const float* __restrict__ h, const float* __restrict__ temb0,
                          bf16* __restrict__ x0, int total) {
    const int i = blockIdx.x * blockDim.x + threadIdx.x;
    if (i < total) x0[i] = __float2bfloat16(h[i] + temb0[i & 511]);
}

extern "C" void kernel_launch(void* const* d_in, const int* in_sizes, int n_in,
                              void* d_out, int out_size, void* d_ws, size_t ws_size,
                              hipStream_t stream) {
    const float* h_in = (const float*)d_in[0];
    const float* W1 = (const float*)d_in[1];
    const float* b1 = (const float*)d_in[2];
    const float* W2 = (const float*)d_in[3];
    const float* b2 = (const float*)d_in[4];
    const float* W3 = (const float*)d_in[5];
    const float* b3 = (const float*)d_in[6];
    const float* Wt = (const float*)d_in[7];
    const float* bt = (const float*)d_in[8];
    // n_steps (d_in[9]) is a fixed Python scalar = 10.
    const int B = 8192, H = 512, H2 = 1024, NS = 10;
    const float dt = 1.f / NS;

    char* ws = (char*)d_ws;
    auto alloc = [&](size_t bytes) {
        char* p = ws;
        ws += (bytes + 255) & ~(size_t)255;
        return p;
    };
    bf16* W1b = (bf16*)alloc((size_t)H2 * H * 2);
    bf16* W2b = (bf16*)alloc((size_t)H2 * H2 * 2);
    bf16* W3b = (bf16*)alloc((size_t)H * H2 * 2);
    bf16* x0b = (bf16*)alloc((size_t)B * H * 2);
    bf16* x1b = (bf16*)alloc((size_t)B * H2 * 2);
    bf16* x2b = (bf16*)alloc((size_t)B * H2 * 2);
    float* kacc = (float*)alloc((size_t)B * H * 4);
    float* temb = (float*)alloc((size_t)21 * H * 4);
    float* hbuf = (float*)d_out;  // h ping-pongs through d_out (fp32)

    {
        int n = H2 * H;
        f2b_kern<<<(n + 255) / 256, 256, 0, stream>>>(W1, W1b, n);
        n = H2 * H2;
        f2b_kern<<<(n + 255) / 256, 256, 0, stream>>>(W2, W2b, n);
        n = H * H2;
        f2b_kern<<<(n + 255) / 256, 256, 0, stream>>>(W3, W3b, n);
    }
    {
        const int total = 21 * H;
        temb_kern<<<(total + 255) / 256, 256, 0, stream>>>(Wt, bt, temb, dt * 0.5f, total);
    }
    {
        const int total = B * H;
        prep_kern<<<(total + 255) / 256, 256, 0, stream>>>(h_in, temb, x0b, total);
    }

    const dim3 blk512(512), blk256(256);
    const dim3 g1(H2 / 128, B / 128);  // 8 x 64  = 512 blocks
    const dim3 g2(H2 / 128, B / 128);  // 8 x 64  = 512 blocks
    const dim3 g3(H / 64, B / 64);     // 8 x 128 = 1024 blocks

    for (int s = 0; s < NS; ++s) {
        const float* hs = (s == 0) ? h_in : hbuf;
        const float* tmid = temb + (size_t)(2 * s + 1) * H;
        const float* tend = temb + (size_t)(2 * s + 2) * H;
        for (int e = 0; e < 4; ++e) {
            gemm_tanh<128, 128, 2, 4><<<g1, blk512, 0, stream>>>(x0b, W1b, b1, x1b, H, H2);
            gemm_tanh<128, 128, 2, 4><<<g2, blk512, 0, stream>>>(x1b, W2b, b2, x2b, H2, H2);
            if (e == 0)
                gemm_k<<<g3, blk256, 0, stream>>>(x2b, W3b, b3, H2, kacc, hs, nullptr,
                                                  x0b, tmid, dt * 0.5f, 0.f, 0);
            else if (e == 1)
                gemm_k<<<g3, blk256, 0, stream>>>(x2b, W3b, b3, H2, kacc, hs, nullptr,
                                                  x0b, tmid, dt * 0.5f, 0.f, 1);
            else if (e == 2)
                gemm_k<<<g3, blk256, 0, stream>>>(x2b, W3b, b3, H2, kacc, hs, nullptr,
                                                  x0b, tend, dt, 0.f, 1);
            else
                gemm_k<<<g3, blk256, 0, stream>>>(x2b, W3b, b3, H2, kacc, hs, hbuf,
                                                  (s == NS - 1) ? nullptr : x0b,
                                                  tend, 0.f, dt / 6.f, 2);
        }
    }
}